// Round 2
// baseline (181.850 us; speedup 1.0000x reference)
//
#include <hip/hip_runtime.h>
#include <hip/hip_bf16.h>
#include <math.h>

// Problem constants: T=4096, B=64, D=64, SCALE = 1/8.
#define T_DIM 4096
#define B_DIM 64
#define D_DIM 64
#define NROWS (T_DIM * B_DIM)   // 262144 (t,b) rows, each 64 floats

// Workspace layout (float offsets)
#define WS_M     0        // 64x64: M[d][d'] = sum_o Wq[o,d]*Wk[o,d']
#define WS_W     4096     // 64: w[d]  = sum_o Wq[o,d]*bk[o]
#define WS_U     4160     // 64: u[d'] = sum_o bq[o]*Wk[o,d']
#define WS_C     4224     // 1:  c     = bq.bk
#define WS_SCORE 8192     // [B][T] scores, overwritten in-place with attn by k3

// ---------------------------------------------------------------------------
// K1: precompute bilinear-form constants. Tiny.
__global__ __launch_bounds__(64) void k1_precompute(
    const float* __restrict__ Wq, const float* __restrict__ bq,
    const float* __restrict__ Wk, const float* __restrict__ bk,
    float* __restrict__ ws) {
  const int tid = threadIdx.x;
  const int blk = blockIdx.x;
  if (blk < 64) {
    const int d = blk;
    float acc = 0.f;
    for (int o = 0; o < 64; ++o)
      acc = fmaf(Wq[o * 64 + d], Wk[o * 64 + tid], acc);
    ws[WS_M + d * 64 + tid] = acc;
  } else {
    float uacc = 0.f, wacc = 0.f, cacc = 0.f;
    for (int o = 0; o < 64; ++o) {
      uacc = fmaf(bq[o], Wk[o * 64 + tid], uacc);
      wacc = fmaf(Wq[o * 64 + tid], bk[o], wacc);
      cacc = fmaf(bq[o], bk[o], cacc);
    }
    ws[WS_U + tid] = uacc;
    ws[WS_W + tid] = wacc;
    if (tid == 0) ws[WS_C] = cacc;
  }
}

// ---------------------------------------------------------------------------
// K2: score[b][t] = SCALE * (e^T M f + w.e + u.f + c).
// ONE WAVE PER BLOCK so `row` is wave-uniform: the f-row loads are uniform
// (s_load -> SGPR broadcast, zero DS/VMEM broadcast cost). Lane d owns M row
// d in VGPRs; FMA is v_fmac(vgpr, sgpr, vgpr).
__global__ __launch_bounds__(64, 4) void k2_score(
    const float* __restrict__ eeg, const float* __restrict__ fnirs,
    const float* __restrict__ Mm, const float* __restrict__ wvec,
    const float* __restrict__ uvec, const float* __restrict__ cvec,
    float* __restrict__ score) {
  const int lane = threadIdx.x;   // 0..63

  float Mrow[64];
  const float4* M4 = reinterpret_cast<const float4*>(Mm) + lane * 16;
#pragma unroll
  for (int j = 0; j < 16; ++j) {
    const float4 m = M4[j];
    Mrow[4 * j + 0] = m.x; Mrow[4 * j + 1] = m.y;
    Mrow[4 * j + 2] = m.z; Mrow[4 * j + 3] = m.w;
  }
  const float wd = wvec[lane];
  const float ud = uvec[lane];
  const float cb = cvec[0];

  for (int row = blockIdx.x; row < NROWS; row += gridDim.x) {
    const float4* __restrict__ fr4 =
        reinterpret_cast<const float4*>(fnirs + row * 64);   // uniform address
    const float e  = eeg[row * 64 + lane];                   // coalesced
    const float fl = fnirs[row * 64 + lane];                 // for u.f term
    float r0 = 0.f, r1 = 0.f, r2 = 0.f, r3 = 0.f;
#pragma unroll
    for (int j = 0; j < 16; ++j) {
      const float4 fj = fr4[j];                              // SGPR broadcast
      r0 = fmaf(Mrow[4 * j + 0], fj.x, r0);
      r1 = fmaf(Mrow[4 * j + 1], fj.y, r1);
      r2 = fmaf(Mrow[4 * j + 2], fj.z, r2);
      r3 = fmaf(Mrow[4 * j + 3], fj.w, r3);
    }
    float contrib = e * (((r0 + r1) + (r2 + r3)) + wd) + ud * fl;
#pragma unroll
    for (int off = 32; off > 0; off >>= 1)
      contrib += __shfl_xor(contrib, off, 64);
    if (lane == 0)
      score[(row & 63) * T_DIM + (row >> 6)] = (contrib + cb) * 0.125f;
  }
}

// ---------------------------------------------------------------------------
// K3: per-b softmax over T=4096 scores; writes attn IN PLACE over score.
__global__ __launch_bounds__(256) void k3_softmax(float* __restrict__ ws) {
  __shared__ float red[8];
  __shared__ float sinv;
  const int b = blockIdx.x;
  const int tid = threadIdx.x;
  float* __restrict__ score = ws + WS_SCORE + b * T_DIM;

  float vals[16];
  float m = -1e30f;
#pragma unroll
  for (int k = 0; k < 16; ++k) {
    vals[k] = score[k * 256 + tid];
    m = fmaxf(m, vals[k]);
  }
#pragma unroll
  for (int off = 32; off > 0; off >>= 1)
    m = fmaxf(m, __shfl_xor(m, off, 64));
  if ((tid & 63) == 0) red[tid >> 6] = m;
  __syncthreads();
  m = fmaxf(fmaxf(red[0], red[1]), fmaxf(red[2], red[3]));

  float s = 0.f;
#pragma unroll
  for (int k = 0; k < 16; ++k) s += __expf(vals[k] - m);
#pragma unroll
  for (int off = 32; off > 0; off >>= 1)
    s += __shfl_xor(s, off, 64);
  if ((tid & 63) == 0) red[4 + (tid >> 6)] = s;
  __syncthreads();
  if (tid == 0) sinv = 1.0f / (red[4] + red[5] + red[6] + red[7]);
  __syncthreads();
  const float inv = sinv;
#pragma unroll
  for (int k = 0; k < 16; ++k)
    score[k * 256 + tid] = __expf(vals[k] - m) * inv;   // attn, in place
}

// ---------------------------------------------------------------------------
// K4: out = eeg + attn * (Wv f + bv). Same wave-uniform-row structure:
// f broadcast via SGPRs, Wv row per lane in VGPRs, attn is one uniform load.
__global__ __launch_bounds__(64, 4) void k4_output(
    const float* __restrict__ eeg, const float* __restrict__ fnirs,
    const float* __restrict__ Wv, const float* __restrict__ bv,
    const float* __restrict__ attn, float* __restrict__ out) {
  const int lane = threadIdx.x;

  float Vrow[64];
  const float4* V4 = reinterpret_cast<const float4*>(Wv) + lane * 16;
#pragma unroll
  for (int j = 0; j < 16; ++j) {
    const float4 m = V4[j];
    Vrow[4 * j + 0] = m.x; Vrow[4 * j + 1] = m.y;
    Vrow[4 * j + 2] = m.z; Vrow[4 * j + 3] = m.w;
  }
  const float bvd = bv[lane];

  for (int row = blockIdx.x; row < NROWS; row += gridDim.x) {
    const float4* __restrict__ fr4 =
        reinterpret_cast<const float4*>(fnirs + row * 64);   // uniform
    const float e = eeg[row * 64 + lane];                    // coalesced
    const float a = attn[(row & 63) * T_DIM + (row >> 6)];   // uniform scalar
    float r0 = 0.f, r1 = 0.f, r2 = 0.f, r3 = 0.f;
#pragma unroll
    for (int j = 0; j < 16; ++j) {
      const float4 fj = fr4[j];
      r0 = fmaf(Vrow[4 * j + 0], fj.x, r0);
      r1 = fmaf(Vrow[4 * j + 1], fj.y, r1);
      r2 = fmaf(Vrow[4 * j + 2], fj.z, r2);
      r3 = fmaf(Vrow[4 * j + 3], fj.w, r3);
    }
    const float v = ((r0 + r1) + (r2 + r3)) + bvd;
    out[row * 64 + lane] = fmaf(a, v, e);                    // coalesced
  }
}

// ---------------------------------------------------------------------------
extern "C" void kernel_launch(void* const* d_in, const int* in_sizes, int n_in,
                              void* d_out, int out_size, void* d_ws, size_t ws_size,
                              hipStream_t stream) {
  const float* eeg   = (const float*)d_in[0];
  const float* fnirs = (const float*)d_in[1];
  const float* Wq    = (const float*)d_in[2];
  const float* bq    = (const float*)d_in[3];
  const float* Wk    = (const float*)d_in[4];
  const float* bk    = (const float*)d_in[5];
  const float* Wv    = (const float*)d_in[6];
  const float* bv    = (const float*)d_in[7];
  float* out = (float*)d_out;
  float* ws  = (float*)d_ws;

  k1_precompute<<<65, 64, 0, stream>>>(Wq, bq, Wk, bk, ws);
  k2_score<<<4096, 64, 0, stream>>>(eeg, fnirs,
                                    ws + WS_M, ws + WS_W, ws + WS_U, ws + WS_C,
                                    ws + WS_SCORE);
  k3_softmax<<<64, 256, 0, stream>>>(ws);
  k4_output<<<4096, 64, 0, stream>>>(eeg, fnirs, Wv, bv, ws + WS_SCORE, out);
}

// Round 3
// 81.723 us; speedup vs baseline: 2.2252x; 2.2252x over previous
//
#include <hip/hip_runtime.h>
#include <hip/hip_bf16.h>
#include <math.h>

// Problem constants: T=4096, B=64, D=64, SCALE = 1/8.
#define T_DIM 4096
#define B_DIM 64
#define D_DIM 64
#define NROWS (T_DIM * B_DIM)   // 262144 rows (r = t*64+b), each 64 floats
#define NTILES (NROWS / 16)     // 16384 16-row MFMA tiles

// Workspace layout (float offsets)
#define WS_M     0        // 64x64: M[d][d'] = sum_o Wq[o,d]*Wk[o,d']
#define WS_W     4096     // 64: w[d]  = sum_o Wq[o,d]*bk[o]
#define WS_U     4160     // 64: u[d'] = sum_o bq[o]*Wk[o,d']
#define WS_C     4224     // 1:  c     = bq.bk
#define WS_SCORE 8192     // [NROWS] scores in natural r order; attn in-place

typedef __attribute__((ext_vector_type(4))) float f32x4;
typedef __attribute__((ext_vector_type(8))) short bf16x8;

static __device__ inline short f2bf(float x) {
  union { float f; unsigned u; } v; v.f = x;
  return (short)((v.u + 0x7FFFu + ((v.u >> 16) & 1u)) >> 16);  // RNE
}

// Load 8 consecutive f32 and convert to a bf16x8 MFMA fragment.
static __device__ inline bf16x8 load_cvt8(const float* __restrict__ p) {
  const float4 a = *reinterpret_cast<const float4*>(p);
  const float4 b = *reinterpret_cast<const float4*>(p + 4);
  bf16x8 r;
  r[0] = f2bf(a.x); r[1] = f2bf(a.y); r[2] = f2bf(a.z); r[3] = f2bf(a.w);
  r[4] = f2bf(b.x); r[5] = f2bf(b.y); r[6] = f2bf(b.z); r[7] = f2bf(b.w);
  return r;
}

// ---------------------------------------------------------------------------
// K1: precompute bilinear-form constants (f32). Tiny.
__global__ __launch_bounds__(64) void k1_precompute(
    const float* __restrict__ Wq, const float* __restrict__ bq,
    const float* __restrict__ Wk, const float* __restrict__ bk,
    float* __restrict__ ws) {
  const int tid = threadIdx.x;
  const int blk = blockIdx.x;
  if (blk < 64) {
    const int d = blk;
    float acc = 0.f;
    for (int o = 0; o < 64; ++o)
      acc = fmaf(Wq[o * 64 + d], Wk[o * 64 + tid], acc);
    ws[WS_M + d * 64 + tid] = acc;
  } else {
    float uacc = 0.f, wacc = 0.f, cacc = 0.f;
    for (int o = 0; o < 64; ++o) {
      uacc = fmaf(bq[o], Wk[o * 64 + tid], uacc);
      wacc = fmaf(Wq[o * 64 + tid], bk[o], wacc);
      cacc = fmaf(bq[o], bk[o], cacc);
    }
    ws[WS_U + tid] = uacc;
    ws[WS_W + tid] = wacc;
    if (tid == 0) ws[WS_C] = cacc;
  }
}

// ---------------------------------------------------------------------------
// K2: score[r] = 0.125*(e_r^T M f_r + w.e_r + u.f_r + c) via MFMA.
// G = F * M~^T per 16-row tile; col-tiles 0..3 = M, col-tile 4 col0 = u.
// B fragments (M~) live in VGPRs for the whole kernel.
__global__ __launch_bounds__(256, 4) void k2_score_mfma(
    const float* __restrict__ eeg, const float* __restrict__ fnirs,
    const float* __restrict__ Mm, const float* __restrict__ wvec,
    const float* __restrict__ uvec, const float* __restrict__ cvec,
    float* __restrict__ score) {
  const int lane = threadIdx.x & 63;
  const int wv   = threadIdx.x >> 6;
  const int wid  = blockIdx.x * 4 + wv;
  const int nwav = gridDim.x * 4;
  const int col  = lane & 15;   // B-col / C-col within tile
  const int grp  = lane >> 4;   // 0..3
  const int kb   = grp * 8;     // k-base within a 32-k half

  // B fragments: B[k=d'][c=d] = M[c][k]  -> 8 contiguous f32 of M row c.
  bf16x8 bf[5][2];
#pragma unroll
  for (int ct = 0; ct < 4; ++ct) {
    const int c = ct * 16 + col;
#pragma unroll
    for (int kf = 0; kf < 2; ++kf)
      bf[ct][kf] = load_cvt8(Mm + c * 64 + kf * 32 + kb);
  }
#pragma unroll
  for (int kf = 0; kf < 2; ++kf) {
    bf16x8 z = (bf16x8)(short)0;
    if (col == 0) z = load_cvt8(uvec + kf * 32 + kb);
    bf[4][kf] = z;
  }
  const float wreg[4] = { wvec[col], wvec[16 + col], wvec[32 + col], wvec[48 + col] };
  const float cb = cvec[0];
  const f32x4 zero = {0.f, 0.f, 0.f, 0.f};

  for (int tile = wid; tile < NTILES; tile += nwav) {
    const int rbase = tile * 16;
    // A fragment: row = rbase + col, k = kb..kb+7 (+32): contiguous 32B f32.
    const float* fa = fnirs + (size_t)(rbase + col) * 64 + kb;
    const bf16x8 a0 = load_cvt8(fa);
    const bf16x8 a1 = load_cvt8(fa + 32);
    f32x4 acc[5];
#pragma unroll
    for (int ct = 0; ct < 5; ++ct) {
      acc[ct] = __builtin_amdgcn_mfma_f32_16x16x32_bf16(a0, bf[ct][0], zero, 0, 0, 0);
      acc[ct] = __builtin_amdgcn_mfma_f32_16x16x32_bf16(a1, bf[ct][1], acc[ct], 0, 0, 0);
    }
    // Epilogue: partial[i] = sum_ct E*(G+w)  (+ u.f + c at col==0), rows grp*4+i.
    float partial[4];
#pragma unroll
    for (int i = 0; i < 4; ++i) {
      const int row = rbase + grp * 4 + i;
      float s = 0.f;
#pragma unroll
      for (int ct = 0; ct < 4; ++ct) {
        const float e = eeg[(size_t)row * 64 + ct * 16 + col];
        s = fmaf(e, acc[ct][i] + wreg[ct], s);
      }
      if (col == 0) s += acc[4][i] + cb;
      partial[i] = s;
    }
#pragma unroll
    for (int m = 8; m >= 1; m >>= 1) {
#pragma unroll
      for (int i = 0; i < 4; ++i)
        partial[i] += __shfl_xor(partial[i], m, 64);
    }
    if (col == 0) {
      float4 o = { partial[0] * 0.125f, partial[1] * 0.125f,
                   partial[2] * 0.125f, partial[3] * 0.125f };
      *reinterpret_cast<float4*>(score + rbase + grp * 4) = o;  // rows 4g..4g+3
    }
  }
}

// ---------------------------------------------------------------------------
// K3: softmax over t (per b); score layout is natural r = t*64+b.
// Strided column access; 1 MB logical, bounded cost. Writes attn in place.
__global__ __launch_bounds__(256) void k3_softmax(float* __restrict__ sc) {
  __shared__ float red[8];
  __shared__ float sinv;
  const int b = blockIdx.x;
  const int tid = threadIdx.x;

  float vals[16];
  float m = -1e30f;
#pragma unroll
  for (int k = 0; k < 16; ++k) {
    vals[k] = sc[(size_t)(k * 256 + tid) * 64 + b];
    m = fmaxf(m, vals[k]);
  }
#pragma unroll
  for (int off = 32; off > 0; off >>= 1)
    m = fmaxf(m, __shfl_xor(m, off, 64));
  if ((tid & 63) == 0) red[tid >> 6] = m;
  __syncthreads();
  m = fmaxf(fmaxf(red[0], red[1]), fmaxf(red[2], red[3]));

  float s = 0.f;
#pragma unroll
  for (int k = 0; k < 16; ++k) s += __expf(vals[k] - m);
#pragma unroll
  for (int off = 32; off > 0; off >>= 1)
    s += __shfl_xor(s, off, 64);
  if ((tid & 63) == 0) red[4 + (tid >> 6)] = s;
  __syncthreads();
  if (tid == 0) sinv = 1.0f / (red[4] + red[5] + red[6] + red[7]);
  __syncthreads();
  const float inv = sinv;
#pragma unroll
  for (int k = 0; k < 16; ++k)
    sc[(size_t)(k * 256 + tid) * 64 + b] = __expf(vals[k] - m) * inv;
}

// ---------------------------------------------------------------------------
// K4: out = eeg + attn * (Wv f + bv) via MFMA. V = F * Wv^T per 16-row tile.
__global__ __launch_bounds__(256, 4) void k4_output_mfma(
    const float* __restrict__ eeg, const float* __restrict__ fnirs,
    const float* __restrict__ Wv, const float* __restrict__ bv,
    const float* __restrict__ attn, float* __restrict__ out) {
  const int lane = threadIdx.x & 63;
  const int wv   = threadIdx.x >> 6;
  const int wid  = blockIdx.x * 4 + wv;
  const int nwav = gridDim.x * 4;
  const int col  = lane & 15;
  const int grp  = lane >> 4;
  const int kb   = grp * 8;

  bf16x8 bf[4][2];
#pragma unroll
  for (int ct = 0; ct < 4; ++ct) {
    const int c = ct * 16 + col;
#pragma unroll
    for (int kf = 0; kf < 2; ++kf)
      bf[ct][kf] = load_cvt8(Wv + c * 64 + kf * 32 + kb);  // B[k][c]=Wv[c][k]
  }
  const float bvreg[4] = { bv[col], bv[16 + col], bv[32 + col], bv[48 + col] };
  const f32x4 zero = {0.f, 0.f, 0.f, 0.f};

  for (int tile = wid; tile < NTILES; tile += nwav) {
    const int rbase = tile * 16;
    const float* fa = fnirs + (size_t)(rbase + col) * 64 + kb;
    const bf16x8 a0 = load_cvt8(fa);
    const bf16x8 a1 = load_cvt8(fa + 32);
    f32x4 acc[4];
#pragma unroll
    for (int ct = 0; ct < 4; ++ct) {
      acc[ct] = __builtin_amdgcn_mfma_f32_16x16x32_bf16(a0, bf[ct][0], zero, 0, 0, 0);
      acc[ct] = __builtin_amdgcn_mfma_f32_16x16x32_bf16(a1, bf[ct][1], acc[ct], 0, 0, 0);
    }
    const float4 a4 = *reinterpret_cast<const float4*>(attn + rbase + grp * 4);
    const float av[4] = { a4.x, a4.y, a4.z, a4.w };
#pragma unroll
    for (int i = 0; i < 4; ++i) {
      const size_t row = rbase + grp * 4 + i;
#pragma unroll
      for (int ct = 0; ct < 4; ++ct) {
        const float e = eeg[row * 64 + ct * 16 + col];
        out[row * 64 + ct * 16 + col] = fmaf(av[i], acc[ct][i] + bvreg[ct], e);
      }
    }
  }
}

// ---------------------------------------------------------------------------
extern "C" void kernel_launch(void* const* d_in, const int* in_sizes, int n_in,
                              void* d_out, int out_size, void* d_ws, size_t ws_size,
                              hipStream_t stream) {
  const float* eeg   = (const float*)d_in[0];
  const float* fnirs = (const float*)d_in[1];
  const float* Wq    = (const float*)d_in[2];
  const float* bq    = (const float*)d_in[3];
  const float* Wk    = (const float*)d_in[4];
  const float* bk    = (const float*)d_in[5];
  const float* Wv    = (const float*)d_in[6];
  const float* bv    = (const float*)d_in[7];
  float* out = (float*)d_out;
  float* ws  = (float*)d_ws;

  k1_precompute<<<65, 64, 0, stream>>>(Wq, bq, Wk, bk, ws);
  k2_score_mfma<<<1024, 256, 0, stream>>>(eeg, fnirs,
                                          ws + WS_M, ws + WS_W, ws + WS_U,
                                          ws + WS_C, ws + WS_SCORE);
  k3_softmax<<<64, 256, 0, stream>>>(ws + WS_SCORE);
  k4_output_mfma<<<1024, 256, 0, stream>>>(eeg, fnirs, Wv, bv,
                                           ws + WS_SCORE, out);
}

// Round 4
// 79.630 us; speedup vs baseline: 2.2837x; 1.0263x over previous
//
#include <hip/hip_runtime.h>
#include <hip/hip_bf16.h>
#include <math.h>

// Problem constants: T=4096, B=64, D=64, SCALE = 1/8.
#define T_DIM 4096
#define B_DIM 64
#define D_DIM 64
#define NROWS (T_DIM * B_DIM)   // 262144 rows (r = t*64+b), each 64 floats
#define NTILES (NROWS / 16)     // 16384 16-row MFMA tiles

// Workspace layout (float offsets)
#define WS_MBF   0        // 64x64 bf16 (2048 floats): M[d][d'] fragment-ready
#define WS_VBF   2048     // 64x64 bf16: Wv[c][k]
#define WS_UBF   4096     // 64 bf16: u[d'] = sum_o bq[o]*Wk[o,d']
#define WS_W     4160     // 64 f32:  w[d]  = sum_o Wq[o,d]*bk[o]
#define WS_C     4224     // 1 f32:   c     = bq.bk
#define WS_SCORE 8192     // [NROWS] scores in natural r order; attn in-place

typedef __attribute__((ext_vector_type(4))) float f32x4;
typedef __attribute__((ext_vector_type(8))) short bf16x8;

static __device__ inline short f2bf(float x) {
  __hip_bfloat16 h = __float2bfloat16(x);   // hardware RNE cvt
  return *reinterpret_cast<short*>(&h);
}

static __device__ inline bf16x8 cvt8(const float4 a, const float4 b) {
  bf16x8 r;
  r[0] = f2bf(a.x); r[1] = f2bf(a.y); r[2] = f2bf(a.z); r[3] = f2bf(a.w);
  r[4] = f2bf(b.x); r[5] = f2bf(b.y); r[6] = f2bf(b.z); r[7] = f2bf(b.w);
  return r;
}

// ---------------------------------------------------------------------------
// K1: precompute bilinear constants; store M, u, Wv as bf16 fragment-ready.
__global__ __launch_bounds__(64) void k1_precompute(
    const float* __restrict__ Wq, const float* __restrict__ bq,
    const float* __restrict__ Wk, const float* __restrict__ bk,
    const float* __restrict__ Wv, float* __restrict__ ws) {
  const int tid = threadIdx.x;
  const int blk = blockIdx.x;
  unsigned short* __restrict__ mbf = (unsigned short*)(ws + WS_MBF);
  unsigned short* __restrict__ vbf = (unsigned short*)(ws + WS_VBF);
  unsigned short* __restrict__ ubf = (unsigned short*)(ws + WS_UBF);
  if (blk < 64) {
    const int d = blk;
    float acc = 0.f;
    for (int o = 0; o < 64; ++o)
      acc = fmaf(Wq[o * 64 + d], Wk[o * 64 + tid], acc);
    mbf[d * 64 + tid] = (unsigned short)f2bf(acc);
    vbf[d * 64 + tid] = (unsigned short)f2bf(Wv[d * 64 + tid]);
  } else {
    float uacc = 0.f, wacc = 0.f, cacc = 0.f;
    for (int o = 0; o < 64; ++o) {
      uacc = fmaf(bq[o], Wk[o * 64 + tid], uacc);
      wacc = fmaf(Wq[o * 64 + tid], bk[o], wacc);
      cacc = fmaf(bq[o], bk[o], cacc);
    }
    ubf[tid] = (unsigned short)f2bf(uacc);
    ws[WS_W + tid] = wacc;
    if (tid == 0) ws[WS_C] = cacc;
  }
}

// ---------------------------------------------------------------------------
// K2: score[r] = 0.125*(e^T M f + w.e + u.f + c). ONE 16-row tile per wave
// (grid 4096x256 = 16384 waves): max TLP, all loads issued up front.
__global__ __launch_bounds__(256, 4) void k2_score_mfma(
    const float* __restrict__ eeg, const float* __restrict__ fnirs,
    const unsigned short* __restrict__ mbf, const float* __restrict__ wvec,
    const unsigned short* __restrict__ ubf, const float* __restrict__ cvec,
    float* __restrict__ score) {
  const int lane = threadIdx.x & 63;
  const int wv   = threadIdx.x >> 6;
  const int tile = blockIdx.x * 4 + wv;    // exactly NTILES waves
  const int col  = lane & 15;
  const int grp  = lane >> 4;
  const int kb   = grp * 8;
  const int rbase = tile * 16;

  // --- data loads first (HBM latency overlaps everything below) ---
  const float* fa = fnirs + (size_t)(rbase + col) * 64 + kb;
  const float4 f0a = *reinterpret_cast<const float4*>(fa);
  const float4 f0b = *reinterpret_cast<const float4*>(fa + 4);
  const float4 f1a = *reinterpret_cast<const float4*>(fa + 32);
  const float4 f1b = *reinterpret_cast<const float4*>(fa + 36);
  float ee[4][4];   // [i][ct]
#pragma unroll
  for (int i = 0; i < 4; ++i)
#pragma unroll
    for (int ct = 0; ct < 4; ++ct)
      ee[i][ct] = eeg[(size_t)(rbase + grp * 4 + i) * 64 + ct * 16 + col];

  // --- weight fragments: bf16, fragment-ready, L2-resident ---
  bf16x8 bm[5][2];
#pragma unroll
  for (int ct = 0; ct < 4; ++ct)
#pragma unroll
    for (int kf = 0; kf < 2; ++kf)
      bm[ct][kf] = *reinterpret_cast<const bf16x8*>(
          mbf + (ct * 16 + col) * 64 + kf * 32 + kb);
#pragma unroll
  for (int kf = 0; kf < 2; ++kf) {
    bf16x8 z = (bf16x8)(short)0;
    if (col == 0)
      z = *reinterpret_cast<const bf16x8*>(ubf + kf * 32 + kb);
    bm[4][kf] = z;
  }
  const float wreg[4] = { wvec[col], wvec[16 + col], wvec[32 + col], wvec[48 + col] };
  const float cb = cvec[0];

  const bf16x8 a0 = cvt8(f0a, f0b);
  const bf16x8 a1 = cvt8(f1a, f1b);
  const f32x4 zero = {0.f, 0.f, 0.f, 0.f};
  f32x4 acc[5];
#pragma unroll
  for (int ct = 0; ct < 5; ++ct) {
    acc[ct] = __builtin_amdgcn_mfma_f32_16x16x32_bf16(a0, bm[ct][0], zero, 0, 0, 0);
    acc[ct] = __builtin_amdgcn_mfma_f32_16x16x32_bf16(a1, bm[ct][1], acc[ct], 0, 0, 0);
  }

  float partial[4];
#pragma unroll
  for (int i = 0; i < 4; ++i) {
    float s = 0.f;
#pragma unroll
    for (int ct = 0; ct < 4; ++ct)
      s = fmaf(ee[i][ct], acc[ct][i] + wreg[ct], s);
    if (col == 0) s += acc[4][i] + cb;
    partial[i] = s;
  }
#pragma unroll
  for (int m = 8; m >= 1; m >>= 1)
#pragma unroll
    for (int i = 0; i < 4; ++i)
      partial[i] += __shfl_xor(partial[i], m, 64);
  if (col == 0) {
    float4 o = { partial[0] * 0.125f, partial[1] * 0.125f,
                 partial[2] * 0.125f, partial[3] * 0.125f };
    *reinterpret_cast<float4*>(score + rbase + grp * 4) = o;
  }
}

// ---------------------------------------------------------------------------
// K3: softmax over t (per b); natural r = t*64+b layout. Attn in place.
__global__ __launch_bounds__(256) void k3_softmax(float* __restrict__ sc) {
  __shared__ float red[8];
  __shared__ float sinv;
  const int b = blockIdx.x;
  const int tid = threadIdx.x;

  float vals[16];
  float m = -1e30f;
#pragma unroll
  for (int k = 0; k < 16; ++k) {
    vals[k] = sc[(size_t)(k * 256 + tid) * 64 + b];
    m = fmaxf(m, vals[k]);
  }
#pragma unroll
  for (int off = 32; off > 0; off >>= 1)
    m = fmaxf(m, __shfl_xor(m, off, 64));
  if ((tid & 63) == 0) red[tid >> 6] = m;
  __syncthreads();
  m = fmaxf(fmaxf(red[0], red[1]), fmaxf(red[2], red[3]));

  float s = 0.f;
#pragma unroll
  for (int k = 0; k < 16; ++k) s += __expf(vals[k] - m);
#pragma unroll
  for (int off = 32; off > 0; off >>= 1)
    s += __shfl_xor(s, off, 64);
  if ((tid & 63) == 0) red[4 + (tid >> 6)] = s;
  __syncthreads();
  if (tid == 0) sinv = 1.0f / (red[4] + red[5] + red[6] + red[7]);
  __syncthreads();
  const float inv = sinv;
#pragma unroll
  for (int k = 0; k < 16; ++k)
    sc[(size_t)(k * 256 + tid) * 64 + b] = __expf(vals[k] - m) * inv;
}

// ---------------------------------------------------------------------------
// K4: out = eeg + attn * (Wv f + bv). One tile per wave, bf16 Wv fragments.
__global__ __launch_bounds__(256, 4) void k4_output_mfma(
    const float* __restrict__ eeg, const float* __restrict__ fnirs,
    const unsigned short* __restrict__ vbf, const float* __restrict__ bv,
    const float* __restrict__ attn, float* __restrict__ out) {
  const int lane = threadIdx.x & 63;
  const int wv   = threadIdx.x >> 6;
  const int tile = blockIdx.x * 4 + wv;
  const int col  = lane & 15;
  const int grp  = lane >> 4;
  const int kb   = grp * 8;
  const int rbase = tile * 16;

  const float* fa = fnirs + (size_t)(rbase + col) * 64 + kb;
  const float4 f0a = *reinterpret_cast<const float4*>(fa);
  const float4 f0b = *reinterpret_cast<const float4*>(fa + 4);
  const float4 f1a = *reinterpret_cast<const float4*>(fa + 32);
  const float4 f1b = *reinterpret_cast<const float4*>(fa + 36);
  float ee[4][4];
#pragma unroll
  for (int i = 0; i < 4; ++i)
#pragma unroll
    for (int ct = 0; ct < 4; ++ct)
      ee[i][ct] = eeg[(size_t)(rbase + grp * 4 + i) * 64 + ct * 16 + col];
  const float4 a4 = *reinterpret_cast<const float4*>(attn + rbase + grp * 4);

  bf16x8 bm[4][2];
#pragma unroll
  for (int ct = 0; ct < 4; ++ct)
#pragma unroll
    for (int kf = 0; kf < 2; ++kf)
      bm[ct][kf] = *reinterpret_cast<const bf16x8*>(
          vbf + (ct * 16 + col) * 64 + kf * 32 + kb);
  const float bvreg[4] = { bv[col], bv[16 + col], bv[32 + col], bv[48 + col] };

  const bf16x8 a0 = cvt8(f0a, f0b);
  const bf16x8 a1 = cvt8(f1a, f1b);
  const f32x4 zero = {0.f, 0.f, 0.f, 0.f};
  f32x4 acc[4];
#pragma unroll
  for (int ct = 0; ct < 4; ++ct) {
    acc[ct] = __builtin_amdgcn_mfma_f32_16x16x32_bf16(a0, bm[ct][0], zero, 0, 0, 0);
    acc[ct] = __builtin_amdgcn_mfma_f32_16x16x32_bf16(a1, bm[ct][1], acc[ct], 0, 0, 0);
  }

  const float av[4] = { a4.x, a4.y, a4.z, a4.w };
#pragma unroll
  for (int i = 0; i < 4; ++i) {
    const size_t row = rbase + grp * 4 + i;
#pragma unroll
    for (int ct = 0; ct < 4; ++ct)
      out[row * 64 + ct * 16 + col] = fmaf(av[i], acc[ct][i] + bvreg[ct], ee[i][ct]);
  }
}

// ---------------------------------------------------------------------------
extern "C" void kernel_launch(void* const* d_in, const int* in_sizes, int n_in,
                              void* d_out, int out_size, void* d_ws, size_t ws_size,
                              hipStream_t stream) {
  const float* eeg   = (const float*)d_in[0];
  const float* fnirs = (const float*)d_in[1];
  const float* Wq    = (const float*)d_in[2];
  const float* bq    = (const float*)d_in[3];
  const float* Wk    = (const float*)d_in[4];
  const float* bk    = (const float*)d_in[5];
  const float* Wv    = (const float*)d_in[6];
  const float* bv    = (const float*)d_in[7];
  float* out = (float*)d_out;
  float* ws  = (float*)d_ws;

  k1_precompute<<<65, 64, 0, stream>>>(Wq, bq, Wk, bk, Wv, ws);
  k2_score_mfma<<<NTILES / 4, 256, 0, stream>>>(
      eeg, fnirs,
      (const unsigned short*)(ws + WS_MBF), ws + WS_W,
      (const unsigned short*)(ws + WS_UBF), ws + WS_C, ws + WS_SCORE);
  k3_softmax<<<64, 256, 0, stream>>>(ws + WS_SCORE);
  k4_output_mfma<<<NTILES / 4, 256, 0, stream>>>(
      eeg, fnirs, (const unsigned short*)(ws + WS_VBF), bv,
      ws + WS_SCORE, out);
}